// Round 8
// baseline (142.361 us; speedup 1.0000x reference)
//
#include <hip/hip_runtime.h>
#include <hip/hip_fp16.h>

#define HH 96
#define WW 96
#define CC 128

typedef float f32x4 __attribute__((ext_vector_type(4)));
typedef short short8 __attribute__((ext_vector_type(8)));
typedef _Float16 f16x8 __attribute__((ext_vector_type(8)));

union U32H2 { unsigned int u; __half2 h; };
__device__ __forceinline__ unsigned int pack2(float x, float y){ U32H2 t; t.h=__floats2half2_rn(x,y); return t.u; }

// f32 -> bf16 round-to-nearest-even
__device__ __forceinline__ unsigned short f2bf(float x){
  unsigned int u = __float_as_uint(x);
  return (unsigned short)((u + 0x7FFFu + ((u >> 16) & 1u)) >> 16);
}
__device__ __forceinline__ unsigned int pkbf(float a, float b){
  return (unsigned)f2bf(a) | ((unsigned)f2bf(b) << 16);
}

union U4S8 { uint4 q; short8 s; };
union U4H8 { uint4 q; f16x8 h; };

// -------------------------------------------------------------------------
// Kernel 1 (MFMA): cost volume via banded GEMM.
// Round-8 = round-7 structure + OOB fix: stage partition is 240 (nxt) +
// 128 (prv) = 368 threads; round-7 let threads 368..383 fall into the prv
// branch (prow_i=2 -> global read past end of prv for the last block, and
// ptile write up to idx 191 > 128 -> LDS overflow) => core dump.
// Block = 384 thr = 6 waves = 2 y-rows x 3 dy-groups (dy = dg*3..dg*3+2).
// acc = [3][2] f32x4 = 24 regs -> ~76 unified regs/lane; (384,6) -> up to
// 6 waves/SIMD. LDS ~35 KB dbuf -> 4 independent 6-wave blocks/CU at
// different stage/MFMA phases (round-6's 2x8-wave blocks stalled together).
// ntile overrun reads (t=1 N-tile) feed only od>8 never-extracted band
// positions (C columns independent under MFMA) — proven rounds 4-6.
// -------------------------------------------------------------------------
__global__ __launch_bounds__(384, 6) void k_cost_mfma(const float* __restrict__ prv,
                                                      const float* __restrict__ nxt,
                                                      __half* __restrict__ cost) {
  const int x0 = blockIdx.x * 16;
  const int y0 = blockIdx.y * 2;       // 2 output rows per block
  const int b  = blockIdx.z;
  const int tid = threadIdx.x;
  const int w = tid >> 6, l = tid & 63;
  const int lm = l & 15, lq = l >> 4;
  const int yr = w & 1, dg = w >> 1;   // y-row 0..1, dy-group 0..2
  const int y = y0 + yr;

  __shared__ uint4 ntile[2][976];      // [(r*4+kq)*24 + p], r 0..9, +overrun pad
  __shared__ uint4 ptile[2][128];      // [(row*4+q)*16 + px]

  f32x4 acc[3][2];
#pragma unroll
  for (int d = 0; d < 3; ++d) {
    acc[d][0] = (f32x4){0.f,0.f,0.f,0.f};
    acc[d][1] = (f32x4){0.f,0.f,0.f,0.f};
  }

  // staging coordinates (hoisted):
  // threads 0..239: nxt 10 halo rows x 24 px, one px each (32 ch/K-step)
  const int srow = tid / 24, scol = tid - 24*srow;
  const int gr = y0 - 4 + srow, gc = x0 - 4 + scol;
  const bool nok = (tid < 240) && ((unsigned)gr < HH) && ((unsigned)gc < WW);
  const float* nrow = &nxt[((size_t)(b*HH + ((unsigned)gr < HH ? gr : 0))*WW
                            + ((unsigned)gc < WW ? gc : 0))*CC];
  // threads 240..367: prv 2 rows x 16 px x 4 kq-quarters (8 ch each)
  const bool pok = (tid >= 240) && (tid < 368);
  const int pidx = pok ? (tid - 240) : 0;
  const int prow_i = pidx >> 6, pq = (pidx >> 4) & 3, ppx = pidx & 15;
  const float* prow = &prv[((size_t)(b*HH + y0 + prow_i)*WW + x0 + ppx)*CC + pq*8];

  auto stage = [&](int ks, int buf){
    if (tid < 240) {
      float4 f[8];
#pragma unroll
      for (int j = 0; j < 8; ++j) f[j] = make_float4(0.f,0.f,0.f,0.f);
      if (nok) {
        const float* src = nrow + ks*32;
#pragma unroll
        for (int j = 0; j < 8; ++j) f[j] = *(const float4*)(src + j*4);
      }
#pragma unroll
      for (int kq = 0; kq < 4; ++kq) {
        uint4 d;
        d.x = pkbf(f[2*kq].x,   f[2*kq].y);
        d.y = pkbf(f[2*kq].z,   f[2*kq].w);
        d.z = pkbf(f[2*kq+1].x, f[2*kq+1].y);
        d.w = pkbf(f[2*kq+1].z, f[2*kq+1].w);
        ntile[buf][(srow*4 + kq)*24 + scol] = d;
      }
    } else if (pok) {
      const float* s = prow + ks*32;
      const float4 a0 = *(const float4*)s;
      const float4 a1 = *(const float4*)(s + 4);
      uint4 pd;
      pd.x = pkbf(a0.x, a0.y); pd.y = pkbf(a0.z, a0.w);
      pd.z = pkbf(a1.x, a1.y); pd.w = pkbf(a1.z, a1.w);
      ptile[buf][(prow_i*4 + pq)*16 + ppx] = pd;
    }
  };

  stage(0, 0);

#pragma unroll 1
  for (int ks = 0; ks < 4; ++ks) {
    __syncthreads();                    // buf[ks&1] ready; buf^1 free
    if (ks < 3) stage(ks + 1, (ks + 1) & 1);

    const int cur = ks & 1;
    U4S8 af;
    af.q = ptile[cur][(yr*4 + lq)*16 + lm];   // A[m=lm][k=lq*8+j]
#pragma unroll
    for (int d = 0; d < 3; ++d) {
      const int sb = ((yr + dg*3 + d)*4 + lq)*24;
      U4S8 b0, b1;
      b0.q = ntile[cur][sb + lm];
      b1.q = ntile[cur][sb + 16 + lm];
      acc[d][0] = __builtin_amdgcn_mfma_f32_16x16x32_bf16(af.s, b0.s, acc[d][0], 0, 0, 0);
      acc[d][1] = __builtin_amdgcn_mfma_f32_16x16x32_bf16(af.s, b1.s, acc[d][1], 0, 0, 0);
    }
  }

  // band extraction: lane holds C[m=lq*4+reg][p=t*16+lm]; od = p - m
  const int ch0 = dg*27;               // dy = dg*3+d -> channel dg*27 + d*9 + od
#pragma unroll
  for (int t = 0; t < 2; ++t) {
#pragma unroll
    for (int reg = 0; reg < 4; ++reg) {
      const int m  = lq*4 + reg;
      const int od = t*16 + lm - m;
      if (od >= 0 && od <= 8) {
        __half* bp = &cost[((size_t)(b*HH + y)*WW + x0 + m)*96 + ch0 + od];
#pragma unroll
        for (int d = 0; d < 3; ++d) {
          float v = acc[d][t][reg] * 0.0078125f;
          v = (v >= 0.f) ? v : 0.1f * v;
          bp[d*9] = __float2half(v);
        }
      }
    }
  }
}

// -------------------------------------------------------------------------
// Kernel 2 (MFMA): conv as GEMM + gather.  (unchanged from round 4)
// G[px, j=tap*2+n] = sum_k feat[px,k] * W[tap,k,n]   (M=324, K=352, N=18->32)
// out[y,x,n] = cb[n] + sum_tap G[y+dy-1, x+dx-1, tap*2+n]
// -------------------------------------------------------------------------
__global__ __launch_bounds__(512) void k_conv_gemm(const float* __restrict__ prv,
                                                   const float* __restrict__ nxt,
                                                   const __half* __restrict__ cost,
                                                   const float* __restrict__ cw,
                                                   const float* __restrict__ cb,
                                                   float* __restrict__ out) {
  const int tw0 = blockIdx.x*16, th0 = blockIdx.y*16, b = blockIdx.z;
  const int tid = threadIdx.x;
  const int w = tid >> 6, l = tid & 63;
  const int lm = l & 15, lq = l >> 4;

  __shared__ __align__(16) char smem[49408];
  uint4*        feat16 = (uint4*)smem;               // [336 px][40 half]
  float*        Gf     = (float*)smem;               // [324][20] f32 (aliased)
  float2*       Gf2    = (float2*)smem;
  uint4*        B2     = (uint4*)(smem + 26880);     // [(kc*4+lq)*32 + j]
  __half*       B2h    = (__half*)(smem + 26880);

#pragma unroll 1
  for (int i = tid; i < 5632; i += 512) ((unsigned int*)B2)[i] = 0u;
#pragma unroll 1
  for (int i = tid; i < 240; i += 512) ((unsigned int*)smem)[6480 + i] = 0u;
#pragma unroll 1
  for (int i = tid; i < 352*18; i += 512) {
    const int ci = i / 18, j = i - 18*ci;
    if (ci >= 81 && ci < 96) continue;
    const int wci = (ci < 81) ? ci : ci - 15;
    const int tap = j >> 1, n = j & 1;
    const float v = cw[(tap*337 + wci)*2 + n];
    const int kk = ci & 31;
    B2h[((((ci >> 5)*4 + (kk >> 3))*32) + j)*8 + (kk & 7)] = __float2half(v);
  }

  f32x4 acc[3][2];
#pragma unroll
  for (int i = 0; i < 3; ++i) { acc[i][0] = (f32x4){0,0,0,0}; acc[i][1] = (f32x4){0,0,0,0}; }

#pragma unroll 1
  for (int kc = 0; kc < 11; ++kc) {
    __syncthreads();
#pragma unroll 1
    for (int i = tid; i < 648; i += 512) {
      const int px = i >> 1, half = i & 1;
      const int hr = px / 18, hc = px - 18*hr;
      const int gr = th0 - 1 + hr, gc = tw0 - 1 + hc;
      uint4 d0 = make_uint4(0,0,0,0), d1 = make_uint4(0,0,0,0);
      if ((unsigned)gr < HH && (unsigned)gc < WW) {
        const size_t pixi = (size_t)(b*HH + gr)*WW + gc;
        if (kc < 3) {
          const uint4* cs = (const uint4*)&cost[pixi*96 + kc*32 + half*16];
          d0 = cs[0]; d1 = cs[1];
        } else {
          const float* src = (kc < 7) ? prv : nxt;
          const int c0 = ((kc < 7) ? (kc-3) : (kc-7))*32 + half*16;
          const float4 f0 = *(const float4*)&src[pixi*128 + c0];
          const float4 f1 = *(const float4*)&src[pixi*128 + c0 + 4];
          const float4 f2 = *(const float4*)&src[pixi*128 + c0 + 8];
          const float4 f3 = *(const float4*)&src[pixi*128 + c0 + 12];
          d0 = make_uint4(pack2(f0.x,f0.y), pack2(f0.z,f0.w), pack2(f1.x,f1.y), pack2(f1.z,f1.w));
          d1 = make_uint4(pack2(f2.x,f2.y), pack2(f2.z,f2.w), pack2(f3.x,f3.y), pack2(f3.z,f3.w));
        }
      }
      feat16[5*px + 2*half]     = d0;
      feat16[5*px + 2*half + 1] = d1;
    }
    __syncthreads();

    U4H8 bf0, bf1;
    bf0.q = B2[(kc*4 + lq)*32 + lm];
    bf1.q = B2[(kc*4 + lq)*32 + 16 + lm];
#pragma unroll
    for (int i = 0; i < 3; ++i) {
      const int mf = w + 8*i;
      if (mf < 21) {
        U4H8 af;
        af.q = feat16[5*(16*mf + lm) + lq];
        acc[i][0] = __builtin_amdgcn_mfma_f32_16x16x32_f16(af.h, bf0.h, acc[i][0], 0, 0, 0);
        acc[i][1] = __builtin_amdgcn_mfma_f32_16x16x32_f16(af.h, bf1.h, acc[i][1], 0, 0, 0);
      }
    }
  }
  __syncthreads();

#pragma unroll
  for (int i = 0; i < 3; ++i) {
    const int mf = w + 8*i;
    if (mf >= 21) continue;
#pragma unroll
    for (int r = 0; r < 4; ++r) {
      const int px = 16*mf + lq*4 + r;
      if (px < 324) {
        Gf[px*20 + lm] = acc[i][0][r];
        if (lm < 2) Gf[px*20 + 16 + lm] = acc[i][1][r];
      }
    }
  }
  __syncthreads();

  if (tid < 512) {
    const int px = tid >> 1, n = tid & 1;
    const int ty = px >> 4, tx = px & 15;
    float s = cb[n];
#pragma unroll
    for (int p = 0; p < 9; ++p) {
      const int dy = p / 3, dx = p - 3*dy;
      const int hp = (ty + dy)*18 + (tx + dx);
      const float2 g = Gf2[hp*10 + p];
      s += n ? g.y : g.x;
    }
    out[((size_t)(b*HH + th0 + ty)*WW + (tw0 + tx))*2 + n] = s;
  }
}

extern "C" void kernel_launch(void* const* d_in, const int* in_sizes, int n_in,
                              void* d_out, int out_size, void* d_ws, size_t ws_size,
                              hipStream_t stream) {
  const float* prv = (const float*)d_in[0];
  const float* nxt = (const float*)d_in[1];
  const float* cw  = (const float*)d_in[2];
  const float* cb  = (const float*)d_in[3];
  __half* cost = (__half*)d_ws;   // 16*96*96*96*2 = 28,311,552 bytes

  k_cost_mfma<<<dim3(6, 48, 16), dim3(384), 0, stream>>>(prv, nxt, cost);
  k_conv_gemm<<<dim3(6, 6, 16), dim3(512), 0, stream>>>(prv, nxt, cost, cw, cb, (float*)d_out);
}

// Round 9
// 115.726 us; speedup vs baseline: 1.2302x; 1.2302x over previous
//
#include <hip/hip_runtime.h>
#include <hip/hip_fp16.h>

#define HH 96
#define WW 96
#define CC 128

#define RS 25   // ntile row stride (uint4 slots), padded 24->25 for bank spread
#define PS 17   // ptile row stride, padded 16->17

typedef float f32x4 __attribute__((ext_vector_type(4)));
typedef short short8 __attribute__((ext_vector_type(8)));
typedef _Float16 f16x8 __attribute__((ext_vector_type(8)));

union U32H2 { unsigned int u; __half2 h; };
__device__ __forceinline__ unsigned int pack2(float x, float y){ U32H2 t; t.h=__floats2half2_rn(x,y); return t.u; }

// f32 -> bf16 round-to-nearest-even
__device__ __forceinline__ unsigned short f2bf(float x){
  unsigned int u = __float_as_uint(x);
  return (unsigned short)((u + 0x7FFFu + ((u >> 16) & 1u)) >> 16);
}
__device__ __forceinline__ unsigned int pkbf(float a, float b){
  return (unsigned)f2bf(a) | ((unsigned)f2bf(b) << 16);
}

union U4S8 { uint4 q; short8 s; };
union U4H8 { uint4 q; f16x8 h; };

// MMA inner step for a dy-range (wave-uniform template)
template<int DY0, int NDY>
static __device__ __forceinline__ void cost_mma(const uint4* __restrict__ nt,
                                                int yr, int lq, int lm,
                                                short8 a, f32x4 (&acc)[5][2]) {
#pragma unroll
  for (int d = 0; d < NDY; ++d) {
    const int sb = ((yr + DY0 + d)*4 + lq)*RS;
    U4S8 b0, b1;
    b0.q = nt[sb + lm];
    b1.q = nt[sb + 16 + lm];
    acc[d][0] = __builtin_amdgcn_mfma_f32_16x16x32_bf16(a, b0.s, acc[d][0], 0, 0, 0);
    acc[d][1] = __builtin_amdgcn_mfma_f32_16x16x32_bf16(a, b1.s, acc[d][1], 0, 0, 0);
  }
}

// -------------------------------------------------------------------------
// Kernel 1 (MFMA): cost volume via banded GEMM.
// Round-9 = round-6 geometry (T=4 y-rows, 8 waves = 4 y x 2 dy-halves,
// acc[5][2]=40 regs, FETCH~190MB) + COALESCED staging:
//  rounds 4-8 measured dur ~= FETCH / 2.0 TB/s regardless of occupancy;
//  old staging was 16B/lane at 512B stride (64 scattered transactions per
//  wave instr). New map: 8 consecutive lanes read the 8 float4 chunks of
//  one pixel's 32-ch slice (128B contiguous per 8 lanes) -> 8x fewer,
//  coalesced transactions. LDS strides padded (24->25, 16->17 uint4) so
//  the uint2-per-thread writes spread uniformly over banks (4/bank for
//  b64 = optimal); MFMA b128 reads stay uniform 2/bank.
// Slot semantics (ch->dword packing), K-loop, band extraction: identical
// to round 6 (proven). ntile t=1 overrun reads feed only od>8 positions
// never extracted (C cols independent under MFMA) - proven rounds 4-8.
// -------------------------------------------------------------------------
__global__ __launch_bounds__(512, 4) void k_cost_mfma(const float* __restrict__ prv,
                                                      const float* __restrict__ nxt,
                                                      __half* __restrict__ cost) {
  const int x0 = blockIdx.x * 16;
  const int y0 = blockIdx.y * 4;       // 4 output rows per block
  const int b  = blockIdx.z;
  const int tid = threadIdx.x;
  const int w = tid >> 6, l = tid & 63;
  const int lm = l & 15, lq = l >> 4;
  const int yr = w >> 1, hf = w & 1;   // y-row 0..3, dy-half
  const int y = y0 + yr;

  __shared__ uint4 ntile[2][1232];     // [(r*4+kq)*25 + p], r 0..11, p 0..23 (+overrun)
  __shared__ uint4 ptile[2][272];      // [(row*4+kq)*17 + px]

  f32x4 acc[5][2];
#pragma unroll
  for (int d = 0; d < 5; ++d) {
    acc[d][0] = (f32x4){0.f,0.f,0.f,0.f};
    acc[d][1] = (f32x4){0.f,0.f,0.f,0.f};
  }

  // prv staging (hoisted): exactly 512 lane-loads: 4 rows x 16 px x 8 ch8
  const int p_px = tid >> 3, p_ch8 = tid & 7;
  const int p_row = p_px >> 4, p_col = p_px & 15;
  const float* prow = &prv[((size_t)(b*HH + y0 + p_row)*WW + x0 + p_col)*CC + p_ch8*4];
  const int p_slot = (p_row*4 + (p_ch8 >> 1))*PS + p_col;
  const int p_half = p_ch8 & 1;

  auto stage = [&](int ks, int buf){
    // nxt: 12 halo rows x 24 px x 8 ch8 = 2304 lane-loads, coalesced
#pragma unroll
    for (int j = 0; j < 5; ++j) {
      const int s = j*512 + tid;
      if (s < 2304) {
        const int px = s >> 3, ch8 = s & 7;
        const int row = px / 24, col = px - 24*row;
        const int gr = y0 - 4 + row, gc = x0 - 4 + col;
        float4 f = make_float4(0.f,0.f,0.f,0.f);
        if ((unsigned)gr < HH && (unsigned)gc < WW)
          f = *(const float4*)&nxt[((size_t)(b*HH + gr)*WW + gc)*CC + ks*32 + ch8*4];
        uint2 d; d.x = pkbf(f.x, f.y); d.y = pkbf(f.z, f.w);
        *(uint2*)((unsigned int*)&ntile[buf][(row*4 + (ch8 >> 1))*RS + col] + (ch8 & 1)*2) = d;
      }
    }
    // prv: 1 lane-load per thread, coalesced
    {
      const float4 f = *(const float4*)(prow + ks*32);
      uint2 d; d.x = pkbf(f.x, f.y); d.y = pkbf(f.z, f.w);
      *(uint2*)((unsigned int*)&ptile[buf][p_slot] + p_half*2) = d;
    }
  };

  stage(0, 0);

#pragma unroll 1
  for (int ks = 0; ks < 4; ++ks) {
    __syncthreads();                    // buf[ks&1] ready; buf^1 free
    if (ks < 3) stage(ks + 1, (ks + 1) & 1);

    const int cur = ks & 1;
    U4S8 af;
    af.q = ptile[cur][(yr*4 + lq)*PS + lm];   // A[m=lm][k=lq*8+j]
    const uint4* nt = ntile[cur];
    if (hf == 0) cost_mma<0,5>(nt, yr, lq, lm, af.s, acc);
    else         cost_mma<5,4>(nt, yr, lq, lm, af.s, acc);
  }

  // band extraction: lane holds C[m=lq*4+reg][p=t*16+lm]; od = p - m
  const int DY0 = hf ? 5 : 0, NDY = hf ? 4 : 5;
#pragma unroll
  for (int t = 0; t < 2; ++t) {
#pragma unroll
    for (int reg = 0; reg < 4; ++reg) {
      const int m  = lq*4 + reg;
      const int od = t*16 + lm - m;
      if (od >= 0 && od <= 8) {
        __half* bp = &cost[((size_t)(b*HH + y)*WW + x0 + m)*96 + DY0*9 + od];
#pragma unroll
        for (int d = 0; d < 5; ++d) {
          if (d < NDY) {                // wave-uniform guard
            float v = acc[d][t][reg] * 0.0078125f;
            v = (v >= 0.f) ? v : 0.1f * v;
            bp[d*9] = __float2half(v);
          }
        }
      }
    }
  }
}

// -------------------------------------------------------------------------
// Kernel 2 (MFMA): conv as GEMM + gather.  (unchanged from round 4)
// G[px, j=tap*2+n] = sum_k feat[px,k] * W[tap,k,n]   (M=324, K=352, N=18->32)
// out[y,x,n] = cb[n] + sum_tap G[y+dy-1, x+dx-1, tap*2+n]
// -------------------------------------------------------------------------
__global__ __launch_bounds__(512) void k_conv_gemm(const float* __restrict__ prv,
                                                   const float* __restrict__ nxt,
                                                   const __half* __restrict__ cost,
                                                   const float* __restrict__ cw,
                                                   const float* __restrict__ cb,
                                                   float* __restrict__ out) {
  const int tw0 = blockIdx.x*16, th0 = blockIdx.y*16, b = blockIdx.z;
  const int tid = threadIdx.x;
  const int w = tid >> 6, l = tid & 63;
  const int lm = l & 15, lq = l >> 4;

  __shared__ __align__(16) char smem[49408];
  uint4*        feat16 = (uint4*)smem;               // [336 px][40 half]
  float*        Gf     = (float*)smem;               // [324][20] f32 (aliased)
  float2*       Gf2    = (float2*)smem;
  uint4*        B2     = (uint4*)(smem + 26880);     // [(kc*4+lq)*32 + j]
  __half*       B2h    = (__half*)(smem + 26880);

#pragma unroll 1
  for (int i = tid; i < 5632; i += 512) ((unsigned int*)B2)[i] = 0u;
#pragma unroll 1
  for (int i = tid; i < 240; i += 512) ((unsigned int*)smem)[6480 + i] = 0u;
#pragma unroll 1
  for (int i = tid; i < 352*18; i += 512) {
    const int ci = i / 18, j = i - 18*ci;
    if (ci >= 81 && ci < 96) continue;
    const int wci = (ci < 81) ? ci : ci - 15;
    const int tap = j >> 1, n = j & 1;
    const float v = cw[(tap*337 + wci)*2 + n];
    const int kk = ci & 31;
    B2h[((((ci >> 5)*4 + (kk >> 3))*32) + j)*8 + (kk & 7)] = __float2half(v);
  }

  f32x4 acc[3][2];
#pragma unroll
  for (int i = 0; i < 3; ++i) { acc[i][0] = (f32x4){0,0,0,0}; acc[i][1] = (f32x4){0,0,0,0}; }

#pragma unroll 1
  for (int kc = 0; kc < 11; ++kc) {
    __syncthreads();
#pragma unroll 1
    for (int i = tid; i < 648; i += 512) {
      const int px = i >> 1, half = i & 1;
      const int hr = px / 18, hc = px - 18*hr;
      const int gr = th0 - 1 + hr, gc = tw0 - 1 + hc;
      uint4 d0 = make_uint4(0,0,0,0), d1 = make_uint4(0,0,0,0);
      if ((unsigned)gr < HH && (unsigned)gc < WW) {
        const size_t pixi = (size_t)(b*HH + gr)*WW + gc;
        if (kc < 3) {
          const uint4* cs = (const uint4*)&cost[pixi*96 + kc*32 + half*16];
          d0 = cs[0]; d1 = cs[1];
        } else {
          const float* src = (kc < 7) ? prv : nxt;
          const int c0 = ((kc < 7) ? (kc-3) : (kc-7))*32 + half*16;
          const float4 f0 = *(const float4*)&src[pixi*128 + c0];
          const float4 f1 = *(const float4*)&src[pixi*128 + c0 + 4];
          const float4 f2 = *(const float4*)&src[pixi*128 + c0 + 8];
          const float4 f3 = *(const float4*)&src[pixi*128 + c0 + 12];
          d0 = make_uint4(pack2(f0.x,f0.y), pack2(f0.z,f0.w), pack2(f1.x,f1.y), pack2(f1.z,f1.w));
          d1 = make_uint4(pack2(f2.x,f2.y), pack2(f2.z,f2.w), pack2(f3.x,f3.y), pack2(f3.z,f3.w));
        }
      }
      feat16[5*px + 2*half]     = d0;
      feat16[5*px + 2*half + 1] = d1;
    }
    __syncthreads();

    U4H8 bf0, bf1;
    bf0.q = B2[(kc*4 + lq)*32 + lm];
    bf1.q = B2[(kc*4 + lq)*32 + 16 + lm];
#pragma unroll
    for (int i = 0; i < 3; ++i) {
      const int mf = w + 8*i;
      if (mf < 21) {
        U4H8 af;
        af.q = feat16[5*(16*mf + lm) + lq];
        acc[i][0] = __builtin_amdgcn_mfma_f32_16x16x32_f16(af.h, bf0.h, acc[i][0], 0, 0, 0);
        acc[i][1] = __builtin_amdgcn_mfma_f32_16x16x32_f16(af.h, bf1.h, acc[i][1], 0, 0, 0);
      }
    }
  }
  __syncthreads();

#pragma unroll
  for (int i = 0; i < 3; ++i) {
    const int mf = w + 8*i;
    if (mf >= 21) continue;
#pragma unroll
    for (int r = 0; r < 4; ++r) {
      const int px = 16*mf + lq*4 + r;
      if (px < 324) {
        Gf[px*20 + lm] = acc[i][0][r];
        if (lm < 2) Gf[px*20 + 16 + lm] = acc[i][1][r];
      }
    }
  }
  __syncthreads();

  if (tid < 512) {
    const int px = tid >> 1, n = tid & 1;
    const int ty = px >> 4, tx = px & 15;
    float s = cb[n];
#pragma unroll
    for (int p = 0; p < 9; ++p) {
      const int dy = p / 3, dx = p - 3*dy;
      const int hp = (ty + dy)*18 + (tx + dx);
      const float2 g = Gf2[hp*10 + p];
      s += n ? g.y : g.x;
    }
    out[((size_t)(b*HH + th0 + ty)*WW + (tw0 + tx))*2 + n] = s;
  }
}

extern "C" void kernel_launch(void* const* d_in, const int* in_sizes, int n_in,
                              void* d_out, int out_size, void* d_ws, size_t ws_size,
                              hipStream_t stream) {
  const float* prv = (const float*)d_in[0];
  const float* nxt = (const float*)d_in[1];
  const float* cw  = (const float*)d_in[2];
  const float* cb  = (const float*)d_in[3];
  __half* cost = (__half*)d_ws;   // 16*96*96*96*2 = 28,311,552 bytes

  k_cost_mfma<<<dim3(6, 24, 16), dim3(512), 0, stream>>>(prv, nxt, cost);
  k_conv_gemm<<<dim3(6, 6, 16), dim3(512), 0, stream>>>(prv, nxt, cost, cw, cb, (float*)d_out);
}